// Round 1
// baseline (475.292 us; speedup 1.0000x reference)
//
#include <hip/hip_runtime.h>

#define BS   1024      // rows per data block
#define DD   128       // feature dim
#define MT   128       // i-rows per workgroup
#define NT   64        // j-rows per tile
#define XI_S 136       // row stride (bf16 elems) for row-major tiles (16B-aligned rows)
#define XT_S 72        // row stride for XjT / P
#define P_OFF (8704 + 9216)

typedef __attribute__((ext_vector_type(8))) short  short8;
typedef __attribute__((ext_vector_type(4))) float  f32x4;
typedef __attribute__((ext_vector_type(4))) unsigned short us4;

__global__ __launch_bounds__(256, 2)
void block_attn_kernel(const float* __restrict__ x, float* __restrict__ out) {
    // union LDS: [0..8703]=XjRM(64x136), [8704..17919]=XjT(128x72, chunk-swizzled),
    // [17920..27135]=P(128x72). Xi staging (128x136=17408) reuses [0..17407] pre-loop.
    __shared__ __align__(16) unsigned short lds[27136];
    __shared__ __align__(16) float csqi[128];
    __shared__ __align__(16) float csqj[64];

    unsigned short* XjRM = lds;
    unsigned short* XjT  = lds + 8704;
    unsigned short* Pm   = lds + P_OFF;

    const int tid  = threadIdx.x;
    const int lane = tid & 63;
    const int wv   = tid >> 6;    // wave 0..3
    const int r16  = lane & 15;
    const int q    = lane >> 4;   // quad 0..3
    const int tr   = tid >> 4;    // 0..15 (staging row group)
    const int tc   = tid & 15;    // 0..15 (staging col group)

    const int b   = blockIdx.x & 255;
    const int mti = blockIdx.x >> 8;
    const int gb  = b * BS;
    const int i0  = gb + mti * MT;

    const float c1 = 0.0390625f;  // 1/25.6
    const float c2 = 0.078125f;   // 2/25.6

    // ---------------- stage Xi (128 rows) into union + csqi ----------------
    #pragma unroll
    for (int half = 0; half < 2; ++half) {
        #pragma unroll
        for (int rr = 0; rr < 4; ++rr) {
            const int row = half * 64 + tr * 4 + rr;
            const float* src = x + (size_t)(i0 + row) * DD + tc * 8;
            const float4 f0 = *(const float4*)src;
            const float4 f1 = *(const float4*)(src + 4);
            const float v[8] = {f0.x, f0.y, f0.z, f0.w, f1.x, f1.y, f1.z, f1.w};
            short8 pk;
            float ssq = 0.f;
            #pragma unroll
            for (int e = 0; e < 8; ++e) {
                const unsigned u = __float_as_uint(v[e]) + 0x8000u;   // RN-ish bf16
                const float ft = __uint_as_float(u & 0xFFFF0000u);    // rounded-back value
                ssq += ft * ft;                                       // sq from ROUNDED vals
                pk[e] = (short)(u >> 16);
            }
            *(short8*)&lds[row * XI_S + tc * 8] = pk;
            #pragma unroll
            for (int o = 1; o < 16; o <<= 1) ssq += __shfl_xor(ssq, o, 64);
            if (tc == rr) csqi[row] = ssq * c1;
        }
    }
    __syncthreads();

    // Xi A-frags live in registers for all 16 j-iters. A[m=lane&15][k=q*8+j]
    short8 afrag[2][4];
    #pragma unroll
    for (int mt = 0; mt < 2; ++mt)
        #pragma unroll
        for (int kk = 0; kk < 4; ++kk)
            afrag[mt][kk] = *(const short8*)&lds[(wv * 32 + mt * 16 + r16) * XI_S + kk * 32 + q * 8];

    f32x4 acc_o[2][8];
    #pragma unroll
    for (int mt = 0; mt < 2; ++mt)
        #pragma unroll
        for (int nt = 0; nt < 8; ++nt)
            acc_o[mt][nt] = (f32x4){0.f, 0.f, 0.f, 0.f};

    __syncthreads();  // all waves done reading Xi staging; union free

    for (int jt = 0; jt < 16; ++jt) {
        const int j0 = jt * NT;

        // ---------------- stage Xj (64 rows): XjRM + swizzled XjT + csqj ----------------
        unsigned short bfv[4][8];
        #pragma unroll
        for (int rr = 0; rr < 4; ++rr) {
            const int row = tr * 4 + rr;
            const float* src = x + (size_t)(gb + j0 + row) * DD + tc * 8;
            const float4 f0 = *(const float4*)src;
            const float4 f1 = *(const float4*)(src + 4);
            const float v[8] = {f0.x, f0.y, f0.z, f0.w, f1.x, f1.y, f1.z, f1.w};
            short8 pk;
            float ssq = 0.f;
            #pragma unroll
            for (int e = 0; e < 8; ++e) {
                const unsigned u = __float_as_uint(v[e]) + 0x8000u;
                const float ft = __uint_as_float(u & 0xFFFF0000u);
                ssq += ft * ft;
                pk[e] = (short)(u >> 16);
                bfv[rr][e] = (unsigned short)(u >> 16);
            }
            *(short8*)&XjRM[row * XI_S + tc * 8] = pk;
            #pragma unroll
            for (int o = 1; o < 16; o <<= 1) ssq += __shfl_xor(ssq, o, 64);
            if (tc == rr) csqj[row] = ssq * c1;
        }
        // transposed store: element (d, j) at d*72 + ((j>>3)^((d>>3)&7))*8 + (j&7)
        #pragma unroll
        for (int ff = 0; ff < 8; ++ff) {
            const int d = tc * 8 + ff;
            us4 tv;
            tv[0] = bfv[0][ff]; tv[1] = bfv[1][ff]; tv[2] = bfv[2][ff]; tv[3] = bfv[3][ff];
            const int off = d * XT_S + ((((tr >> 1) ^ (tc & 7)) << 3) | ((tr & 1) << 2));
            *(us4*)&XjT[off] = tv;
        }
        __syncthreads();

        // ---------------- S = Xi · Xjᵀ (wave: rows wv*32..+32, cols 0..63) ----------------
        f32x4 acc_s[2][4];
        #pragma unroll
        for (int mt = 0; mt < 2; ++mt)
            #pragma unroll
            for (int nt = 0; nt < 4; ++nt)
                acc_s[mt][nt] = (f32x4){0.f, 0.f, 0.f, 0.f};
        #pragma unroll
        for (int nt = 0; nt < 4; ++nt) {
            #pragma unroll
            for (int kk = 0; kk < 4; ++kk) {
                const short8 bf = *(const short8*)&XjRM[(nt * 16 + r16) * XI_S + kk * 32 + q * 8];
                acc_s[0][nt] = __builtin_amdgcn_mfma_f32_16x16x32_bf16(afrag[0][kk], bf, acc_s[0][nt], 0, 0, 0);
                acc_s[1][nt] = __builtin_amdgcn_mfma_f32_16x16x32_bf16(afrag[1][kk], bf, acc_s[1][nt], 0, 0, 0);
            }
        }

        // ---------------- w = exp(-max(d2,0)/25.6) -> P (wave's own rows) ----------------
        #pragma unroll
        for (int mt = 0; mt < 2; ++mt) {
            const int rowb = wv * 32 + mt * 16 + q * 4;   // C-layout row base
            const f32x4 ci = *(const f32x4*)&csqi[rowb];
            #pragma unroll
            for (int nt = 0; nt < 4; ++nt) {
                const float cj = csqj[nt * 16 + r16];
                #pragma unroll
                for (int rg = 0; rg < 4; ++rg) {
                    float arg = acc_s[mt][nt][rg] * c2 - (ci[rg] + cj);
                    arg = fminf(arg, 0.f);                 // == clamp d2 >= 0
                    const float wval = __expf(arg);
                    Pm[(rowb + rg) * XT_S + nt * 16 + r16] =
                        (unsigned short)((__float_as_uint(wval) + 0x8000u) >> 16);
                }
            }
        }

        // ---------------- O += P · Xj  (A = own P rows, B = XjT; no barrier needed) -----
        #pragma unroll
        for (int kk = 0; kk < 2; ++kk) {
            short8 pf[2];
            #pragma unroll
            for (int mt = 0; mt < 2; ++mt)
                pf[mt] = *(const short8*)&Pm[(wv * 32 + mt * 16 + r16) * XT_S + kk * 32 + q * 8];
            #pragma unroll
            for (int nt = 0; nt < 8; ++nt) {
                const int d = nt * 16 + r16;
                const int chunk = (kk * 4 + q) ^ ((d >> 3) & 7);
                const short8 bf = *(const short8*)&XjT[d * XT_S + (chunk << 3)];
                acc_o[0][nt] = __builtin_amdgcn_mfma_f32_16x16x32_bf16(pf[0], bf, acc_o[0][nt], 0, 0, 0);
                acc_o[1][nt] = __builtin_amdgcn_mfma_f32_16x16x32_bf16(pf[1], bf, acc_o[1][nt], 0, 0, 0);
            }
        }
        __syncthreads();  // XjRM/XjT reused next iter
    }

    // ---------------- epilogue: O / 1024 -> out ----------------
    const float sc = 1.0f / 1024.0f;
    #pragma unroll
    for (int mt = 0; mt < 2; ++mt) {
        #pragma unroll
        for (int nt = 0; nt < 8; ++nt) {
            #pragma unroll
            for (int rg = 0; rg < 4; ++rg) {
                const int row = i0 + wv * 32 + mt * 16 + q * 4 + rg;
                out[(size_t)row * DD + nt * 16 + r16] = acc_o[mt][nt][rg] * sc;
            }
        }
    }
}

extern "C" void kernel_launch(void* const* d_in, const int* in_sizes, int n_in,
                              void* d_out, int out_size, void* d_ws, size_t ws_size,
                              hipStream_t stream) {
    (void)in_sizes; (void)n_in; (void)out_size; (void)d_ws; (void)ws_size;
    const float* x = (const float*)d_in[0];
    float* out = (float*)d_out;
    // 256 data blocks x 8 i-tiles; bid&255 = block -> same-XCD L2 reuse of block X
    block_attn_kernel<<<dim3(2048), dim3(256), 0, stream>>>(x, out);
}

// Round 2
// 382.814 us; speedup vs baseline: 1.2416x; 1.2416x over previous
//
#include <hip/hip_runtime.h>

#define BS   1024
#define DD   128

typedef __attribute__((ext_vector_type(8))) short  short8;
typedef __attribute__((ext_vector_type(4))) float  f32x4;
typedef __attribute__((ext_vector_type(4))) unsigned short us4;

#define AS1 __attribute__((address_space(1)))
#define AS3 __attribute__((address_space(3)))

static __device__ __forceinline__ void gl_lds16(const void* g, void* l) {
    __builtin_amdgcn_global_load_lds((const AS1 unsigned int*)g,
                                     (AS3 unsigned int*)l, 16, 0, 0);
}

// ---------------------------------------------------------------------------
// Pass 1: fp32 X -> (a) row-major bf16, XOR-8 16B-chunk swizzle per row
//                   (b) per-block transposed XT bf16 [block][jt][d][j-chunk swz]
//                   (c) sq[row] * (1/25.6)
// ---------------------------------------------------------------------------
__global__ __launch_bounds__(256, 4)
void pass1_convert(const float* __restrict__ x, unsigned short* __restrict__ xrm,
                   unsigned short* __restrict__ xt, float* __restrict__ sqg) {
    __shared__ unsigned short tile[64 * 130];   // bf16 slice, stride 130 (2-way free)
    const int t = threadIdx.x;
    const int b = blockIdx.x >> 4;
    const int s = blockIdx.x & 15;

    // phase a: 64 rows x 128 d; thread t: row r=t>>2, quarter q4=t&3 (32 floats)
    const int r  = t >> 2, q4 = t & 3;
    const int grow = b * BS + s * 64 + r;
    const float* src = x + (size_t)grow * DD + q4 * 32;
    float ssq = 0.f;
    #pragma unroll
    for (int cc = 0; cc < 4; ++cc) {
        const float4 f0 = *(const float4*)(src + cc * 8);
        const float4 f1 = *(const float4*)(src + cc * 8 + 4);
        const float v[8] = {f0.x, f0.y, f0.z, f0.w, f1.x, f1.y, f1.z, f1.w};
        unsigned int dw[4];
        #pragma unroll
        for (int p = 0; p < 4; ++p) {
            const unsigned u0 = __float_as_uint(v[2 * p]) + 0x8000u;
            const unsigned u1 = __float_as_uint(v[2 * p + 1]) + 0x8000u;
            const float t0 = __uint_as_float(u0 & 0xFFFF0000u);
            const float t1 = __uint_as_float(u1 & 0xFFFF0000u);
            ssq += t0 * t0 + t1 * t1;
            dw[p] = (u0 >> 16) | (u1 & 0xFFFF0000u);
        }
        const int c = q4 * 4 + cc;
        // global RM write (swizzled chunk)
        *(uint4*)((char*)xrm + (size_t)grow * 256 + ((c ^ (r & 7)) << 4)) =
            make_uint4(dw[0], dw[1], dw[2], dw[3]);
        // LDS write for transpose (plain layout)
        const int e0 = r * 130 + q4 * 32 + cc * 8;
        *(unsigned int*)&tile[e0]     = dw[0];
        *(unsigned int*)&tile[e0 + 2] = dw[1];
        *(unsigned int*)&tile[e0 + 4] = dw[2];
        *(unsigned int*)&tile[e0 + 6] = dw[3];
    }
    ssq += __shfl_xor(ssq, 1);
    ssq += __shfl_xor(ssq, 2);
    if (q4 == 0) sqg[grow] = ssq * 0.0390625f;   // sq / 25.6
    __syncthreads();

    // phase b: write XT[b][s][d 0..127][swizzled j-chunk 0..7]
    const int jg = t & 7;
    #pragma unroll
    for (int it = 0; it < 4; ++it) {
        const int dl = (t >> 3) + 32 * it;
        unsigned int dw[4];
        #pragma unroll
        for (int p = 0; p < 4; ++p) {
            const unsigned h0 = tile[(jg * 8 + 2 * p) * 130 + dl];
            const unsigned h1 = tile[(jg * 8 + 2 * p + 1) * 130 + dl];
            dw[p] = h0 | (h1 << 16);
        }
        *(uint4*)((char*)xt + (size_t)(b * 16 + s) * 16384 + dl * 128 +
                  ((jg ^ (dl & 7)) << 4)) = make_uint4(dw[0], dw[1], dw[2], dw[3]);
    }
}

// ---------------------------------------------------------------------------
// Main kernel: per wg = (block b, i-tile 128 rows).
// LDS: [0..16383]B XjRM (64x256B swz) | [16384..32767]B XjT (128x128B swz)
//      (both regions = Xi staging 32KB at init) | [32768..51199]B P (128x144B)
// ---------------------------------------------------------------------------
__global__ __launch_bounds__(256, 3)
void block_attn_mx(const unsigned short* __restrict__ xrm,
                   const unsigned short* __restrict__ xt,
                   const float* __restrict__ sqg, float* __restrict__ out) {
    __shared__ __align__(16) unsigned short lds[25600];
    unsigned short* XjT = lds + 8192;    // elem index (byte 16384)
    unsigned short* Pm  = lds + 16384;   // byte 32768, stride 72 elems (144 B)

    const int tid  = threadIdx.x;
    const int lane = tid & 63;
    const int wv   = tid >> 6;
    const int r16  = lane & 15;
    const int q    = lane >> 4;
    const int sw   = r16 & 7;            // frag-read swizzle key

    const unsigned w = blockIdx.x;
    const int b  = ((w >> 6) << 3) + (w & 7);   // all 8 tiles of b on one XCD, adjacent
    const int ti = (w >> 3) & 7;
    const int i0 = b * BS + ti * 128;

    const float c2 = 0.078125f;          // 2/25.6

    // ---- stage Xi (32 KB) via global_load_lds, identity copy ----
    {
        const char* srcb = (const char*)xrm + (size_t)i0 * 256;
        #pragma unroll
        for (int k = 0; k < 8; ++k) {
            const int off = (wv * 8 + k) * 1024;
            gl_lds16(srcb + off + lane * 16, (void*)((char*)lds + off));
        }
    }
    __syncthreads();

    // Xi B-frags (persist in registers): B[n=i][k=d]
    short8 xi[2][4];
    #pragma unroll
    for (int im = 0; im < 2; ++im)
        #pragma unroll
        for (int kk = 0; kk < 4; ++kk)
            xi[im][kk] = *(const short8*)&lds[(wv * 32 + im * 16 + r16) * 128 +
                                             (((kk * 4 + q) ^ sw) << 3)];
    const float ci0 = sqg[i0 + wv * 32 + r16];
    const float ci1 = sqg[i0 + wv * 32 + 16 + r16];

    f32x4 acc_o[2][8];
    #pragma unroll
    for (int im = 0; im < 2; ++im)
        #pragma unroll
        for (int nt = 0; nt < 8; ++nt)
            acc_o[im][nt] = (f32x4){0.f, 0.f, 0.f, 0.f};

    for (int jt = 0; jt < 16; ++jt) {
        __syncthreads();   // previous buffers (or Xi frag reads) complete
        // ---- stage XjRM (waves 0,1) + XjT (waves 2,3), 8 x 1KB each ----
        if (wv < 2) {
            const char* srcb = (const char*)xrm + (size_t)(b * BS + jt * 64) * 256;
            #pragma unroll
            for (int k = 0; k < 8; ++k) {
                const int off = (wv * 8 + k) * 1024;
                gl_lds16(srcb + off + lane * 16, (void*)((char*)lds + off));
            }
        } else {
            const char* srcb = (const char*)xt + (size_t)(b * 16 + jt) * 16384;
            #pragma unroll
            for (int k = 0; k < 8; ++k) {
                const int off = ((wv - 2) * 8 + k) * 1024;
                gl_lds16(srcb + off + lane * 16, (void*)((char*)lds + 16384 + off));
            }
        }
        __syncthreads();   // staging complete (barrier drains vmcnt)

        // ---- S^T tile-by-tile: A = Xj rows (LDS), B = Xi rows (regs) ----
        // C row = j-local = q*4+rg, col = i-local = r16  -> P store contiguous b64
        #pragma unroll
        for (int jn = 0; jn < 4; ++jn) {
            f32x4 a0 = (f32x4){0.f, 0.f, 0.f, 0.f};
            f32x4 a1 = (f32x4){0.f, 0.f, 0.f, 0.f};
            #pragma unroll
            for (int kk = 0; kk < 4; ++kk) {
                const short8 xj = *(const short8*)&lds[(jn * 16 + r16) * 128 +
                                                       (((kk * 4 + q) ^ sw) << 3)];
                a0 = __builtin_amdgcn_mfma_f32_16x16x32_bf16(xj, xi[0][kk], a0, 0, 0, 0);
                a1 = __builtin_amdgcn_mfma_f32_16x16x32_bf16(xj, xi[1][kk], a1, 0, 0, 0);
            }
            const f32x4 sj = *(const f32x4*)&sqg[b * BS + jt * 64 + jn * 16 + q * 4];
            #pragma unroll
            for (int im = 0; im < 2; ++im) {
                const f32x4 a = im ? a1 : a0;
                const float ci = im ? ci1 : ci0;
                us4 hv;
                #pragma unroll
                for (int rg = 0; rg < 4; ++rg) {
                    float arg = fmaf(a[rg], c2, -(sj[rg] + ci));
                    arg = fminf(arg, 0.f);
                    hv[rg] = (unsigned short)((__float_as_uint(__expf(arg)) + 0x8000u) >> 16);
                }
                // P[i = wv*32+im*16+r16][j = jn*16+q*4 .. +3]
                *(us4*)&Pm[(wv * 32 + im * 16 + r16) * 72 + jn * 16 + q * 4] = hv;
            }
        }

        // ---- O += P · Xj : A = own P rows, B = XjT (no barrier needed) ----
        #pragma unroll
        for (int kk = 0; kk < 2; ++kk) {
            const short8 pf0 = *(const short8*)&Pm[(wv * 32 + r16) * 72 + kk * 32 + q * 8];
            const short8 pf1 = *(const short8*)&Pm[(wv * 32 + 16 + r16) * 72 + kk * 32 + q * 8];
            #pragma unroll
            for (int nt = 0; nt < 8; ++nt) {
                const short8 bf = *(const short8*)&XjT[(nt * 16 + r16) * 64 +
                                                       (((kk * 4 + q) ^ sw) << 3)];
                acc_o[0][nt] = __builtin_amdgcn_mfma_f32_16x16x32_bf16(pf0, bf, acc_o[0][nt], 0, 0, 0);
                acc_o[1][nt] = __builtin_amdgcn_mfma_f32_16x16x32_bf16(pf1, bf, acc_o[1][nt], 0, 0, 0);
            }
        }
    }

    // ---- epilogue ----
    const float sc = 1.0f / 1024.0f;
    #pragma unroll
    for (int im = 0; im < 2; ++im)
        #pragma unroll
        for (int nt = 0; nt < 8; ++nt)
            #pragma unroll
            for (int rg = 0; rg < 4; ++rg) {
                const int row = i0 + wv * 32 + im * 16 + q * 4 + rg;
                out[(size_t)row * DD + nt * 16 + r16] = acc_o[im][nt][rg] * sc;
            }
}

// ---------------------------------------------------------------------------
// Fallback (round-1 kernel, passes): used only if ws_size is too small.
// ---------------------------------------------------------------------------
#define XI_S 136
#define XT_S 72
#define P_OFF (8704 + 9216)

__global__ __launch_bounds__(256, 2)
void block_attn_kernel(const float* __restrict__ x, float* __restrict__ out) {
    __shared__ __align__(16) unsigned short lds[27136];
    __shared__ __align__(16) float csqi[128];
    __shared__ __align__(16) float csqj[64];

    unsigned short* XjRM = lds;
    unsigned short* XjT  = lds + 8704;
    unsigned short* Pm   = lds + P_OFF;

    const int tid  = threadIdx.x;
    const int lane = tid & 63;
    const int wv   = tid >> 6;
    const int r16  = lane & 15;
    const int q    = lane >> 4;
    const int tr   = tid >> 4;
    const int tc   = tid & 15;

    const int b   = blockIdx.x & 255;
    const int mti = blockIdx.x >> 8;
    const int gb  = b * BS;
    const int i0  = gb + mti * 128;

    const float c1 = 0.0390625f;
    const float c2 = 0.078125f;

    #pragma unroll
    for (int half = 0; half < 2; ++half) {
        #pragma unroll
        for (int rr = 0; rr < 4; ++rr) {
            const int row = half * 64 + tr * 4 + rr;
            const float* src = x + (size_t)(i0 + row) * DD + tc * 8;
            const float4 f0 = *(const float4*)src;
            const float4 f1 = *(const float4*)(src + 4);
            const float v[8] = {f0.x, f0.y, f0.z, f0.w, f1.x, f1.y, f1.z, f1.w};
            short8 pk;
            float ssq = 0.f;
            #pragma unroll
            for (int e = 0; e < 8; ++e) {
                const unsigned u = __float_as_uint(v[e]) + 0x8000u;
                const float ft = __uint_as_float(u & 0xFFFF0000u);
                ssq += ft * ft;
                pk[e] = (short)(u >> 16);
            }
            *(short8*)&lds[row * XI_S + tc * 8] = pk;
            #pragma unroll
            for (int o = 1; o < 16; o <<= 1) ssq += __shfl_xor(ssq, o, 64);
            if (tc == rr) csqi[row] = ssq * c1;
        }
    }
    __syncthreads();

    short8 afrag[2][4];
    #pragma unroll
    for (int mt = 0; mt < 2; ++mt)
        #pragma unroll
        for (int kk = 0; kk < 4; ++kk)
            afrag[mt][kk] = *(const short8*)&lds[(wv * 32 + mt * 16 + r16) * XI_S + kk * 32 + q * 8];

    f32x4 acc_o[2][8];
    #pragma unroll
    for (int mt = 0; mt < 2; ++mt)
        #pragma unroll
        for (int nt = 0; nt < 8; ++nt)
            acc_o[mt][nt] = (f32x4){0.f, 0.f, 0.f, 0.f};

    __syncthreads();

    for (int jt = 0; jt < 16; ++jt) {
        const int j0 = jt * 64;
        unsigned short bfv[4][8];
        #pragma unroll
        for (int rr = 0; rr < 4; ++rr) {
            const int row = tr * 4 + rr;
            const float* src = x + (size_t)(gb + j0 + row) * DD + tc * 8;
            const float4 f0 = *(const float4*)src;
            const float4 f1 = *(const float4*)(src + 4);
            const float v[8] = {f0.x, f0.y, f0.z, f0.w, f1.x, f1.y, f1.z, f1.w};
            short8 pk;
            float ssq = 0.f;
            #pragma unroll
            for (int e = 0; e < 8; ++e) {
                const unsigned u = __float_as_uint(v[e]) + 0x8000u;
                const float ft = __uint_as_float(u & 0xFFFF0000u);
                ssq += ft * ft;
                pk[e] = (short)(u >> 16);
                bfv[rr][e] = (unsigned short)(u >> 16);
            }
            *(short8*)&XjRM[row * XI_S + tc * 8] = pk;
            #pragma unroll
            for (int o = 1; o < 16; o <<= 1) ssq += __shfl_xor(ssq, o, 64);
            if (tc == rr) csqj[row] = ssq * c1;
        }
        #pragma unroll
        for (int ff = 0; ff < 8; ++ff) {
            const int d = tc * 8 + ff;
            us4 tv;
            tv[0] = bfv[0][ff]; tv[1] = bfv[1][ff]; tv[2] = bfv[2][ff]; tv[3] = bfv[3][ff];
            const int off = d * XT_S + ((((tr >> 1) ^ (tc & 7)) << 3) | ((tr & 1) << 2));
            *(us4*)&XjT[off] = tv;
        }
        __syncthreads();

        f32x4 acc_s[2][4];
        #pragma unroll
        for (int mt = 0; mt < 2; ++mt)
            #pragma unroll
            for (int nt = 0; nt < 4; ++nt)
                acc_s[mt][nt] = (f32x4){0.f, 0.f, 0.f, 0.f};
        #pragma unroll
        for (int nt = 0; nt < 4; ++nt) {
            #pragma unroll
            for (int kk = 0; kk < 4; ++kk) {
                const short8 bf = *(const short8*)&XjRM[(nt * 16 + r16) * XI_S + kk * 32 + q * 8];
                acc_s[0][nt] = __builtin_amdgcn_mfma_f32_16x16x32_bf16(afrag[0][kk], bf, acc_s[0][nt], 0, 0, 0);
                acc_s[1][nt] = __builtin_amdgcn_mfma_f32_16x16x32_bf16(afrag[1][kk], bf, acc_s[1][nt], 0, 0, 0);
            }
        }

        #pragma unroll
        for (int mt = 0; mt < 2; ++mt) {
            const int rowb = wv * 32 + mt * 16 + q * 4;
            const f32x4 ci = *(const f32x4*)&csqi[rowb];
            #pragma unroll
            for (int nt = 0; nt < 4; ++nt) {
                const float cj = csqj[nt * 16 + r16];
                #pragma unroll
                for (int rg = 0; rg < 4; ++rg) {
                    float arg = acc_s[mt][nt][rg] * c2 - (ci[rg] + cj);
                    arg = fminf(arg, 0.f);
                    const float wval = __expf(arg);
                    Pm[(rowb + rg) * XT_S + nt * 16 + r16] =
                        (unsigned short)((__float_as_uint(wval) + 0x8000u) >> 16);
                }
            }
        }

        #pragma unroll
        for (int kk = 0; kk < 2; ++kk) {
            short8 pf[2];
            #pragma unroll
            for (int mt = 0; mt < 2; ++mt)
                pf[mt] = *(const short8*)&Pm[(wv * 32 + mt * 16 + r16) * XT_S + kk * 32 + q * 8];
            #pragma unroll
            for (int nt = 0; nt < 8; ++nt) {
                const int d = nt * 16 + r16;
                const int chunk = (kk * 4 + q) ^ ((d >> 3) & 7);
                const short8 bf = *(const short8*)&XjT[d * XT_S + (chunk << 3)];
                acc_o[0][nt] = __builtin_amdgcn_mfma_f32_16x16x32_bf16(pf[0], bf, acc_o[0][nt], 0, 0, 0);
                acc_o[1][nt] = __builtin_amdgcn_mfma_f32_16x16x32_bf16(pf[1], bf, acc_o[1][nt], 0, 0, 0);
            }
        }
        __syncthreads();
    }

    const float sc = 1.0f / 1024.0f;
    #pragma unroll
    for (int mt = 0; mt < 2; ++mt)
        #pragma unroll
        for (int nt = 0; nt < 8; ++nt)
            #pragma unroll
            for (int rg = 0; rg < 4; ++rg) {
                const int row = i0 + wv * 32 + mt * 16 + q * 4 + rg;
                out[(size_t)row * DD + nt * 16 + r16] = acc_o[mt][nt][rg] * sc;
            }
}

extern "C" void kernel_launch(void* const* d_in, const int* in_sizes, int n_in,
                              void* d_out, int out_size, void* d_ws, size_t ws_size,
                              hipStream_t stream) {
    (void)in_sizes; (void)n_in; (void)out_size;
    const float* x = (const float*)d_in[0];
    float* out = (float*)d_out;

    const size_t XRM_BYTES = (size_t)262144 * 256;        // 67,108,864
    const size_t XT_BYTES  = (size_t)256 * 16 * 16384;    // 67,108,864
    const size_t SQ_BYTES  = (size_t)262144 * 4;          // 1,048,576

    if (ws_size >= XRM_BYTES + XT_BYTES + SQ_BYTES) {
        unsigned short* xrm = (unsigned short*)d_ws;
        unsigned short* xt  = (unsigned short*)((char*)d_ws + XRM_BYTES);
        float*          sq  = (float*)((char*)d_ws + XRM_BYTES + XT_BYTES);
        pass1_convert<<<dim3(4096), dim3(256), 0, stream>>>(x, xrm, xt, sq);
        block_attn_mx<<<dim3(2048), dim3(256), 0, stream>>>(xrm, xt, sq, out);
    } else {
        block_attn_kernel<<<dim3(2048), dim3(256), 0, stream>>>(x, out);
    }
}